// Round 1
// 1511.445 us; speedup vs baseline: 2.2314x; 2.2314x over previous
//
#include <hip/hip_runtime.h>
#include <hip/hip_bf16.h>
#include <math.h>

#define CC 256
#define CQn 32
#define HH 64
#define WW 64
#define NN 4096
#define EPSF 1e-5f

typedef __hip_bfloat16 bf16;

__device__ __forceinline__ float b2f(bf16 v) { return __bfloat162float(v); }
__device__ __forceinline__ bf16 f2b(float v) { return __float2bfloat16(v); }

template<typename T> __device__ __forceinline__ float ldf(const T* p, size_t i);
template<> __device__ __forceinline__ float ldf<float>(const float* p, size_t i) { return p[i]; }
template<> __device__ __forceinline__ float ldf<bf16>(const bf16* p, size_t i)  { return b2f(p[i]); }

__device__ __forceinline__ void stf(float* p, size_t i, float v) { p[i] = v; }
__device__ __forceinline__ void stf(bf16* p, size_t i, float v)  { p[i] = f2b(v); }

// ---------------- K0: dtype detector ----------------
__global__ __launch_bounds__(256)
void detect_kernel(const unsigned short* __restrict__ x1, int* __restrict__ flag)
{
    __shared__ int bad;
    if (threadIdx.x == 0) bad = 0;
    __syncthreads();
    int mybad = 0;
    for (int i = threadIdx.x; i < 16384; i += 256) {
        unsigned short u = x1[i];
        if ((u & 0x7F80u) == 0x7F80u) mybad = 1;
    }
    if (mybad) atomicOr(&bad, 1);
    __syncthreads();
    if (threadIdx.x == 0) *flag = bad ? 1 : 0;
}

// ---------------- K1: Sobel conv3x3 + BN + magnitude ----------------
template<typename T>
__global__ __launch_bounds__(256)
void sobel_kernel(const int* __restrict__ dflag, int want,
                  const T* __restrict__ x1, const T* __restrict__ x2,
                  const T* __restrict__ wx1, const T* __restrict__ wy1,
                  const T* __restrict__ bnx1, const T* __restrict__ bny1,
                  const T* __restrict__ wx2, const T* __restrict__ wy2,
                  const T* __restrict__ bnx2, const T* __restrict__ bny2,
                  bf16* __restrict__ xf1, bf16* __restrict__ xf2)
{
    if (*dflag != want) return;
    const int z = blockIdx.z;
    const T* x   = z ? x2   : x1;
    const T* wx  = z ? wx2  : wx1;
    const T* wy  = z ? wy2  : wy1;
    const T* bnx = z ? bnx2 : bnx1;
    const T* bny = z ? bny2 : bny1;
    bf16* xf = z ? xf2 : xf1;

    const int tile = blockIdx.x;          // 0..3, 2x2 of 32x32
    const int ty0 = (tile >> 1) * 32;
    const int tx0 = (tile & 1) * 32;
    const int o0 = blockIdx.y * 8;

    const int tid = threadIdx.x;
    const int lx  = tid & 31;
    const int ly0 = (tid >> 5) * 4;       // 0..28 step 4

    __shared__ float xt[34 * 34];
    __shared__ float wl[8 * 20];

    float accx[8][4], accy[8][4];
    #pragma unroll
    for (int o = 0; o < 8; ++o)
        #pragma unroll
        for (int r = 0; r < 4; ++r) { accx[o][r] = 0.f; accy[o][r] = 0.f; }

    for (int ci = 0; ci < CC; ++ci) {
        for (int idx = tid; idx < 34 * 34; idx += 256) {
            int r = idx / 34, cc = idx - r * 34;
            int gy = ty0 + r - 1, gx = tx0 + cc - 1;
            float v = 0.f;
            if (gy >= 0 && gy < HH && gx >= 0 && gx < WW)
                v = ldf(x, (size_t)ci * NN + gy * WW + gx);
            xt[idx] = v;
        }
        if (tid < 144) {
            int o = tid / 18, k = tid - o * 18;
            const T* wsrc = (k < 9) ? wx : wy;
            wl[o * 20 + k] = ldf(wsrc, (size_t)((o0 + o) * CC + ci) * 9 + (k % 9));
        }
        __syncthreads();

        float xv[6][3];
        #pragma unroll
        for (int r = 0; r < 6; ++r)
            #pragma unroll
            for (int c = 0; c < 3; ++c)
                xv[r][c] = xt[(ly0 + r) * 34 + lx + c];

        #pragma unroll
        for (int o = 0; o < 8; ++o) {
            float w[18];
            #pragma unroll
            for (int k = 0; k < 18; ++k) w[k] = wl[o * 20 + k];
            #pragma unroll
            for (int pr = 0; pr < 4; ++pr) {
                float sx = 0.f, sy = 0.f;
                #pragma unroll
                for (int ky = 0; ky < 3; ++ky)
                    #pragma unroll
                    for (int kx = 0; kx < 3; ++kx) {
                        float xi = xv[pr + ky][kx];
                        sx = fmaf(w[ky * 3 + kx], xi, sx);
                        sy = fmaf(w[9 + ky * 3 + kx], xi, sy);
                    }
                accx[o][pr] += sx;
                accy[o][pr] += sy;
            }
        }
        __syncthreads();
    }

    #pragma unroll
    for (int o = 0; o < 8; ++o) {
        int oc = o0 + o;
        float invx = ldf(bnx, oc) * rsqrtf(ldf(bnx, 3 * CC + oc) + EPSF);
        float bx   = ldf(bnx, CC + oc);
        float mx   = ldf(bnx, 2 * CC + oc);
        float invy = ldf(bny, oc) * rsqrtf(ldf(bny, 3 * CC + oc) + EPSF);
        float by   = ldf(bny, CC + oc);
        float my   = ldf(bny, 2 * CC + oc);
        #pragma unroll
        for (int pr = 0; pr < 4; ++pr) {
            float gxn = (accx[o][pr] - mx) * invx + bx;
            float gyn = (accy[o][pr] - my) * invy + by;
            int py = ty0 + ly0 + pr, px = tx0 + lx;
            xf[oc * NN + py * WW + px] = f2b(sqrtf(gxn * gxn + gyn * gyn));
        }
    }
}

// ---------------- K2: 1x1 convs (q,k,v for both attends) ----------------
template<typename T>
__global__ __launch_bounds__(256)
void qkv_kernel(const int* __restrict__ dflag, int want,
                const T* __restrict__ x1, const T* __restrict__ x2,
                const bf16* __restrict__ xf1, const bf16* __restrict__ xf2,
                const T* __restrict__ q1w, const T* __restrict__ q1b,
                const T* __restrict__ k1w, const T* __restrict__ k1b,
                const T* __restrict__ v1w, const T* __restrict__ v1b,
                const T* __restrict__ q2w, const T* __restrict__ q2b,
                const T* __restrict__ k2w, const T* __restrict__ k2b,
                const T* __restrict__ v2w, const T* __restrict__ v2b,
                float* __restrict__ q1t, float* __restrict__ k1t, bf16* __restrict__ v1t,
                float* __restrict__ q2t, float* __restrict__ k2t, bf16* __restrict__ v2t)
{
    if (*dflag != want) return;
    const int z = blockIdx.z;
    const T* Wb; const T* bias;
    const T* Xt = nullptr; const bf16* Xb = nullptr;
    float* outF = nullptr; bf16* outB = nullptr; int O;
    switch (z) {
        case 0:  Wb = q1w; bias = q1b; Xt = x1;  outF = q1t; O = CQn; break;
        case 1:  Wb = k1w; bias = k1b; Xb = xf2; outF = k1t; O = CQn; break;
        case 2:  Wb = v1w; bias = v1b; Xb = xf2; outB = v1t; O = CC;  break;
        case 3:  Wb = q2w; bias = q2b; Xt = x2;  outF = q2t; O = CQn; break;
        case 4:  Wb = k2w; bias = k2b; Xb = xf1; outF = k2t; O = CQn; break;
        default: Wb = v2w; bias = v2b; Xb = xf1; outB = v2t; O = CC;  break;
    }
    const int o0 = blockIdx.x * 32;
    if (o0 >= O) return;
    const int n0 = blockIdx.y * 512;
    const int tid = threadIdx.x;

    __shared__ float lw[32 * 256];        // lw[o][c]
    for (int idx = tid; idx < 32 * 256; idx += 256)
        lw[idx] = ldf(Wb, (size_t)o0 * CC + idx);
    __syncthreads();

    const int n_a = n0 + tid;
    const int n_b = n0 + 256 + tid;

    float acca[32], accb[32];
    #pragma unroll
    for (int o = 0; o < 32; ++o) { acca[o] = 0.f; accb[o] = 0.f; }

    const float4* lw4 = (const float4*)lw;
    for (int c4 = 0; c4 < 64; ++c4) {
        float xa[4], xb[4];
        #pragma unroll
        for (int k = 0; k < 4; ++k) {
            size_t ia = (size_t)(c4 * 4 + k) * NN + n_a;
            size_t ib = (size_t)(c4 * 4 + k) * NN + n_b;
            if (Xt) { xa[k] = ldf(Xt, ia); xb[k] = ldf(Xt, ib); }
            else    { xa[k] = b2f(Xb[ia]); xb[k] = b2f(Xb[ib]); }
        }
        #pragma unroll
        for (int o = 0; o < 32; ++o) {
            float4 w4 = lw4[o * 64 + c4];
            acca[o] = fmaf(w4.x, xa[0], fmaf(w4.y, xa[1], fmaf(w4.z, xa[2], fmaf(w4.w, xa[3], acca[o]))));
            accb[o] = fmaf(w4.x, xb[0], fmaf(w4.y, xb[1], fmaf(w4.z, xb[2], fmaf(w4.w, xb[3], accb[o]))));
        }
    }
    #pragma unroll
    for (int o = 0; o < 32; ++o) {
        float bb = ldf(bias, o0 + o);
        acca[o] += bb; accb[o] += bb;
    }
    if (outF) {
        float* da = outF + (size_t)n_a * O + o0;
        float* db = outF + (size_t)n_b * O + o0;
        #pragma unroll
        for (int o4 = 0; o4 < 8; ++o4) {
            ((float4*)da)[o4] = make_float4(acca[o4*4], acca[o4*4+1], acca[o4*4+2], acca[o4*4+3]);
            ((float4*)db)[o4] = make_float4(accb[o4*4], accb[o4*4+1], accb[o4*4+2], accb[o4*4+3]);
        }
    } else {
        bf16* da = outB + (size_t)n_a * O + o0;
        bf16* db = outB + (size_t)n_b * O + o0;
        #pragma unroll
        for (int o = 0; o < 32; ++o) { da[o] = f2b(acca[o]); db[o] = f2b(accb[o]); }
    }
}

// ---------------- K3: flash attention (restructured, online softmax) ----------------
// Block = 256 threads handles 16 queries x all 4096 keys.
// Grid = 512 blocks (2 att x 256 q-tiles) -> 2 blocks/CU, 8 waves/CU.
// Per k-tile (64 keys):
//   phase A: stage K tile to LDS (coalesced float4)
//   phase B: thread (q=tid>>4, jg=tid&15) computes 4 energies in regs (Q held
//            in VGPRs for the whole kernel), shfl_xor online-softmax over its
//            16-lane group, writes exp'd P to LDS.  No idle lanes.
//   phase C: thread (qg=tid>>5 -> 2 q, cl=tid&31 -> 8 c) PV update: 16B uint4
//            V loads (8 bf16), float4 broadcast P reads, 32 FMA per P value.
// 2 barriers per k-tile. Epilogue transposes through LDS for coalesced stores.
__device__ __forceinline__ void pv4(uint4 v, float ps0, float ps1,
                                    float* __restrict__ acc0, float* __restrict__ acc1)
{
    unsigned u[4] = { v.x, v.y, v.z, v.w };
    #pragma unroll
    for (int k = 0; k < 4; ++k) {
        float fl = __uint_as_float(u[k] << 16);
        float fh = __uint_as_float(u[k] & 0xffff0000u);
        acc0[2*k]   = fmaf(fl, ps0, acc0[2*k]);
        acc0[2*k+1] = fmaf(fh, ps0, acc0[2*k+1]);
        acc1[2*k]   = fmaf(fl, ps1, acc1[2*k]);
        acc1[2*k+1] = fmaf(fh, ps1, acc1[2*k+1]);
    }
}

template<typename T>
__global__ __launch_bounds__(256)
void attend_kernel(const int* __restrict__ dflag, int want,
                   const float* __restrict__ q1t, const float* __restrict__ k1t,
                   const bf16* __restrict__ v1t, const T* __restrict__ x1,
                   const T* __restrict__ g1,
                   const float* __restrict__ q2t, const float* __restrict__ k2t,
                   const bf16* __restrict__ v2t, const T* __restrict__ x2,
                   const T* __restrict__ g2,
                   T* __restrict__ out)
{
    if (*dflag != want) return;
    const int att = blockIdx.x >> 8;
    const int i0 = (blockIdx.x & 255) * 16;
    const float* qt = att ? q2t : q1t;
    const float* kt = att ? k2t : k1t;
    const bf16* vt  = att ? v2t : v1t;
    const T* xq = att ? x2 : x1;
    const T* gp = att ? g2 : g1;
    T* o = out + (size_t)att * CC * NN;

    const int tid = threadIdx.x;

    // 4160 floats reused as [64][36] K + [16][68] P during main loop, then as
    // [16][260] output transpose buffer. m/l/a live past the reuse region.
    __shared__ float smem[4208];
    float* k_lds = smem;            // 64*36 = 2304
    float* p_lds = smem + 2304;     // 16*68 = 1088 (ends 3392 < 4160)
    float* m_s   = smem + 4160;     // 16
    float* l_s   = smem + 4176;     // 16
    float* a_s   = smem + 4192;     // 16

    const int sq = tid >> 4, jg = tid & 15;   // softmax/QK mapping
    const int qg = tid >> 5, cl = tid & 31;   // PV mapping

    // Q row (32 floats) held in registers for the whole kernel
    float4 qv[8];
    {
        const float4* qp = (const float4*)(qt + (size_t)(i0 + sq) * CQn);
        #pragma unroll
        for (int c4 = 0; c4 < 8; ++c4) qv[c4] = qp[c4];
    }

    if (tid < 16) { m_s[tid] = -INFINITY; l_s[tid] = 0.f; }

    float acc0[8], acc1[8];
    #pragma unroll
    for (int dc = 0; dc < 8; ++dc) { acc0[dc] = 0.f; acc1[dc] = 0.f; }

    for (int jt = 0; jt < 64; ++jt) {
        const int j0 = jt * 64;

        // ---- phase A: stage K tile ----
        {
            const int j = tid >> 2, c8 = (tid & 3) * 8;
            const float4* src = (const float4*)(kt + (size_t)(j0 + j) * CQn + c8);
            float4 a = src[0], b = src[1];
            float4* dst = (float4*)(k_lds + j * 36 + c8);
            dst[0] = a; dst[1] = b;
        }
        __syncthreads();

        // ---- phase B: QK^T + online softmax (all 256 lanes busy) ----
        {
            float e[4];
            #pragma unroll
            for (int jj = 0; jj < 4; ++jj) {
                const float4* kr = (const float4*)(k_lds + (jj * 16 + jg) * 36);
                float s = 0.f;
                #pragma unroll
                for (int c4 = 0; c4 < 8; ++c4) {
                    float4 kv = kr[c4];
                    s = fmaf(qv[c4].x, kv.x, s);
                    s = fmaf(qv[c4].y, kv.y, s);
                    s = fmaf(qv[c4].z, kv.z, s);
                    s = fmaf(qv[c4].w, kv.w, s);
                }
                e[jj] = s;
            }
            float tm = fmaxf(fmaxf(e[0], e[1]), fmaxf(e[2], e[3]));
            #pragma unroll
            for (int msk = 1; msk <= 8; msk <<= 1)
                tm = fmaxf(tm, __shfl_xor(tm, msk));
            const float mo = m_s[sq];
            const float mn = fmaxf(mo, tm);
            float s = 0.f;
            #pragma unroll
            for (int jj = 0; jj < 4; ++jj) {
                float p = __expf(e[jj] - mn);
                p_lds[sq * 68 + jj * 16 + jg] = p;
                s += p;
            }
            #pragma unroll
            for (int msk = 1; msk <= 8; msk <<= 1)
                s += __shfl_xor(s, msk);
            if (jg == 0) {
                float alpha = __expf(mo - mn);
                a_s[sq] = alpha;
                m_s[sq] = mn;
                l_s[sq] = l_s[sq] * alpha + s;
            }
        }
        __syncthreads();

        // ---- phase C: PV (2 q x 8 c per thread; 32 FMA per LDS read) ----
        {
            const float a0 = a_s[qg * 2 + 0], a1 = a_s[qg * 2 + 1];
            #pragma unroll
            for (int dc = 0; dc < 8; ++dc) { acc0[dc] *= a0; acc1[dc] *= a1; }
            const float* pr0 = p_lds + (qg * 2 + 0) * 68;
            const float* pr1 = p_lds + (qg * 2 + 1) * 68;
            const bf16* vb = vt + (size_t)j0 * CC + cl * 8;
            #pragma unroll 4
            for (int j4 = 0; j4 < 16; ++j4) {
                const float4 p0 = *(const float4*)(pr0 + j4 * 4);
                const float4 p1 = *(const float4*)(pr1 + j4 * 4);
                uint4 v[4];
                #pragma unroll
                for (int u = 0; u < 4; ++u)
                    v[u] = *(const uint4*)(vb + (size_t)(j4 * 4 + u) * CC);
                pv4(v[0], p0.x, p1.x, acc0, acc1);
                pv4(v[1], p0.y, p1.y, acc0, acc1);
                pv4(v[2], p0.z, p1.z, acc0, acc1);
                pv4(v[3], p0.w, p1.w, acc0, acc1);
            }
        }
        // No barrier needed here: next phase A only touches k_lds, whose
        // readers all passed the phase-B barrier; p_lds/a_s writers wait at
        // the next phase-A barrier.
    }

    // ---- epilogue: transpose via LDS for coalesced-ish stores ----
    __syncthreads();              // all PV reads of p_lds done
    float* ot = smem;             // [16][260]
    #pragma unroll
    for (int dc = 0; dc < 8; ++dc) {
        ot[(qg * 2 + 0) * 260 + cl * 8 + dc] = acc0[dc];
        ot[(qg * 2 + 1) * 260 + cl * 8 + dc] = acc1[dc];
    }
    __syncthreads();
    {
        const float g = ldf(gp, 0);
        const int eq = tid & 15, cg = tid >> 4;
        const float rl = 1.0f / l_s[eq];
        #pragma unroll
        for (int i = 0; i < 16; ++i) {
            const int c = cg * 16 + i;
            float v = ot[eq * 260 + c];
            float xv = ldf(xq, (size_t)c * NN + i0 + eq);
            stf(o, (size_t)c * NN + i0 + eq, fmaf(g, v * rl, xv));
        }
    }
}

extern "C" void kernel_launch(void* const* d_in, const int* in_sizes, int n_in,
                              void* d_out, int out_size, void* d_ws, size_t ws_size,
                              hipStream_t stream) {
    // workspace: 256B flag header + 10.0 MB buffers (ws_size >= 11MB proven in R3)
    if (ws_size < (size_t)(10 * 1024 * 1024 + 512 * 1024)) return;

    int* dflag = (int*)d_ws;
    char* base = (char*)d_ws + 256;
    bf16* xf1 = (bf16*)base;               // 1048576 bf16 (2 MB)
    bf16* xf2 = xf1 + 1048576;             // 2 MB
    bf16* v1t = xf2 + 1048576;             // 2 MB
    bf16* v2t = v1t + 1048576;             // 2 MB
    float* q1t = (float*)(v2t + 1048576);  // 0.5 MB
    float* k1t = q1t + 131072;             // 0.5 MB
    float* q2t = k1t + 131072;             // 0.5 MB
    float* k2t = q2t + 131072;             // 0.5 MB

    detect_kernel<<<dim3(1), 256, 0, stream>>>((const unsigned short*)d_in[0], dflag);

    // ---- bf16 pipeline (want=0) ----
    {
        typedef bf16 T;
        sobel_kernel<T><<<dim3(4, 32, 2), 256, 0, stream>>>(dflag, 0,
            (const T*)d_in[0], (const T*)d_in[1],
            (const T*)d_in[2], (const T*)d_in[3], (const T*)d_in[4], (const T*)d_in[5],
            (const T*)d_in[6], (const T*)d_in[7], (const T*)d_in[8], (const T*)d_in[9],
            xf1, xf2);
        qkv_kernel<T><<<dim3(8, 8, 6), 256, 0, stream>>>(dflag, 0,
            (const T*)d_in[0], (const T*)d_in[1], xf1, xf2,
            (const T*)d_in[10], (const T*)d_in[11], (const T*)d_in[12], (const T*)d_in[13],
            (const T*)d_in[14], (const T*)d_in[15], (const T*)d_in[16], (const T*)d_in[17],
            (const T*)d_in[18], (const T*)d_in[19], (const T*)d_in[20], (const T*)d_in[21],
            q1t, k1t, v1t, q2t, k2t, v2t);
        attend_kernel<T><<<dim3(512), 256, 0, stream>>>(dflag, 0,
            q1t, k1t, v1t, (const T*)d_in[0], (const T*)d_in[22],
            q2t, k2t, v2t, (const T*)d_in[1], (const T*)d_in[23],
            (T*)d_out);
    }
    // ---- f32 pipeline (want=1) ----
    {
        typedef float T;
        sobel_kernel<T><<<dim3(4, 32, 2), 256, 0, stream>>>(dflag, 1,
            (const T*)d_in[0], (const T*)d_in[1],
            (const T*)d_in[2], (const T*)d_in[3], (const T*)d_in[4], (const T*)d_in[5],
            (const T*)d_in[6], (const T*)d_in[7], (const T*)d_in[8], (const T*)d_in[9],
            xf1, xf2);
        qkv_kernel<T><<<dim3(8, 8, 6), 256, 0, stream>>>(dflag, 1,
            (const T*)d_in[0], (const T*)d_in[1], xf1, xf2,
            (const T*)d_in[10], (const T*)d_in[11], (const T*)d_in[12], (const T*)d_in[13],
            (const T*)d_in[14], (const T*)d_in[15], (const T*)d_in[16], (const T*)d_in[17],
            (const T*)d_in[18], (const T*)d_in[19], (const T*)d_in[20], (const T*)d_in[21],
            q1t, k1t, v1t, q2t, k2t, v2t);
        attend_kernel<T><<<dim3(512), 256, 0, stream>>>(dflag, 1,
            q1t, k1t, v1t, (const T*)d_in[0], (const T*)d_in[22],
            q2t, k2t, v2t, (const T*)d_in[1], (const T*)d_in[23],
            (T*)d_out);
    }
}